// Round 11
// baseline (166.811 us; speedup 1.0000x reference)
//
#include <hip/hip_runtime.h>
#include <math.h>

// Resonator: out = (input + comb(bandpass(delay_buffer))) * gain
//
// bandpass: y1[n]=a1*y1[n-1]+(1-a1)*x[n]; y2[n]=a2*y2[n-1]+(1-a2)*a1*(x[n]-y1[n-1])
// comb over frames j (L=960): z[j] = fb*(filt[j-1]+z[j-1]), z[0]=0
//
// Pipeline (exact except filter's 256-sample zero-state halo, a1^256~1.2e-3):
//   K1 filter:  buf -> filt                         (LDS-staged, skew-36, b128)
//   K2 sums:    S[b][c] = sum_t fb^(16-t) filt[16b+t][c]    (reads filt once)
//   K3 scan:    Z[b][c] = z at frame 16b via z' = fb^16 z + S_b  (exact)
//   K4 produce: from Z checkpoint, 16 frames/thread, each element touched once
//
// CKPT=16 (not 64): K2/K4 get 245,760 threads (~15 waves/CU) -- R6's CKPT=64
// was latency-bound at 3.75 waves/CU.

constexpr int N_SAMPLES = 7864320;
constexpr int L_FRAME   = 960;
constexpr int K_FRAMES  = 8192;
constexpr int CKPT      = 16;
constexpr int NBLK      = K_FRAMES / CKPT;   // 512
constexpr int C2        = L_FRAME / 2;       // 480 float2 columns

// ---- K1: filter ----
constexpr int T1    = 32;
constexpr int BLK1  = 256;
constexpr int TILE1 = BLK1 * T1;             // 8192
constexpr int HALO1 = 256;
constexpr int STAGE_F4 = (TILE1 + HALO1) / 4;          // 2112
__device__ __forceinline__ int skew(int b) { return b + 4 * (b >> 5); }
constexpr int XS_FLOATS = (TILE1 + HALO1) + 4 * ((TILE1 + HALO1) / 32) + 4;

__global__ __launch_bounds__(256)
void filter_kernel(const float* __restrict__ buf,
                   const float* __restrict__ params,
                   float* __restrict__ filt) {
    __shared__ __align__(16) float xs[XS_FLOATS];   // ~38 KB -> 4 blocks/CU
    const int t     = threadIdx.x;
    const int tile0 = blockIdx.x * TILE1;

    const float4* b4 = reinterpret_cast<const float4*>(buf);
    const int g0 = tile0 / 4 - HALO1 / 4;
    for (int i = t; i < STAGE_F4; i += BLK1) {
        const int gi = g0 + i;
        const float4 v = (gi >= 0) ? b4[gi] : make_float4(0.f, 0.f, 0.f, 0.f);
        *reinterpret_cast<float4*>(&xs[skew(4 * i)]) = v;
    }
    __syncthreads();

    const float TPS = 6.28318530717958647692f / 48000.0f;
    const float a1 = expf(-TPS * params[2]);
    const float a2 = expf(-TPS * params[3]);
    const float k1 = 1.0f - a1;
    const float k2 = (1.0f - a2) * a1;

    float y1 = 0.f, y2 = 0.f;
    float o[T1];

#define FSTEP(v) do { float xv = (v); y2 = a2*y2 + k2*(xv - y1); y1 = a1*y1 + k1*xv; } while (0)
    for (int s = 0; s < 8; ++s) {           // warm-up [t*32, t*32+256)
        const int base = 36 * (t + s);
        #pragma unroll
        for (int r4 = 0; r4 < 8; ++r4) {
            const float4 x = *reinterpret_cast<const float4*>(&xs[base + 4 * r4]);
            FSTEP(x.x); FSTEP(x.y); FSTEP(x.z); FSTEP(x.w);
        }
    }
    {   // produce [t*32+256, t*32+288)
        const int base = 36 * (t + 8);
        #pragma unroll
        for (int r4 = 0; r4 < 8; ++r4) {
            const float4 x = *reinterpret_cast<const float4*>(&xs[base + 4 * r4]);
            FSTEP(x.x); o[4*r4]   = y2;
            FSTEP(x.y); o[4*r4+1] = y2;
            FSTEP(x.z); o[4*r4+2] = y2;
            FSTEP(x.w); o[4*r4+3] = y2;
        }
    }
#undef FSTEP
    __syncthreads();
    {
        const int base = 36 * t;
        #pragma unroll
        for (int r4 = 0; r4 < 8; ++r4)
            *reinterpret_cast<float4*>(&xs[base + 4 * r4]) =
                make_float4(o[4*r4], o[4*r4+1], o[4*r4+2], o[4*r4+3]);
    }
    __syncthreads();
    float4* f4 = reinterpret_cast<float4*>(filt);
    for (int i = t; i < TILE1 / 4; i += BLK1)
        f4[tile0 / 4 + i] = *reinterpret_cast<const float4*>(&xs[skew(4 * i)]);
}

// ---- K2: S[b][c2] = sum_t fb^(CKPT-t) filt[CKPT*b+t][c2] ----
__global__ __launch_bounds__(256)
void sums_kernel(const float* __restrict__ filt,
                 const float* __restrict__ params,
                 float* __restrict__ S) {
    const int tid = blockIdx.x * blockDim.x + threadIdx.x;
    if (tid >= C2 * NBLK) return;
    const int c2 = tid % C2;
    const int b  = tid / C2;
    const float fb = params[1];

    const float2* f2p = reinterpret_cast<const float2*>(filt);
    float2 s = make_float2(0.f, 0.f);
    int idx = (b * CKPT) * C2 + c2;
    #pragma unroll
    for (int t = 0; t < CKPT; t += 4) {
        const float2 f0 = f2p[idx];
        const float2 f1 = f2p[idx + C2];
        const float2 f2v = f2p[idx + 2 * C2];
        const float2 f3 = f2p[idx + 3 * C2];
        s.x = fb * (s.x + f0.x);  s.y = fb * (s.y + f0.y);
        s.x = fb * (s.x + f1.x);  s.y = fb * (s.y + f1.y);
        s.x = fb * (s.x + f2v.x); s.y = fb * (s.y + f2v.y);
        s.x = fb * (s.x + f3.x);  s.y = fb * (s.y + f3.y);
        idx += 4 * C2;
    }
    reinterpret_cast<float2*>(S)[b * C2 + c2] = s;   // z[16(b+1)] = fb^16 z[16b] + S_b
}

// ---- K3: checkpoint scan; 480 threads, 512 steps, unroll-32 load batching ----
__global__ __launch_bounds__(256)
void scan_kernel(const float* __restrict__ S,
                 const float* __restrict__ params,
                 float* __restrict__ Z) {
    const int c2 = blockIdx.x * blockDim.x + threadIdx.x;
    if (c2 >= C2) return;
    const float fb = params[1];
    float fbk = fb;                         // fb^16 by repeated squaring
    for (int i = 0; i < 4; ++i) fbk *= fbk;

    const float2* S2 = reinterpret_cast<const float2*>(S);
    float2*       Z2 = reinterpret_cast<float2*>(Z);
    float2 z = make_float2(0.f, 0.f);
    for (int b = 0; b < NBLK; b += 32) {    // 16 batches
        float2 sv[32];
        #pragma unroll
        for (int k = 0; k < 32; ++k) sv[k] = S2[(b + k) * C2 + c2];
        #pragma unroll
        for (int k = 0; k < 32; ++k) {
            Z2[(b + k) * C2 + c2] = z;
            z.x = fbk * z.x + sv[k].x;
            z.y = fbk * z.y + sv[k].y;
        }
    }
}

// ---- K4: produce output; each element touched exactly once ----
__global__ __launch_bounds__(256)
void produce_kernel(const float* __restrict__ filt,
                    const float* __restrict__ input,
                    const float* __restrict__ Z,
                    const float* __restrict__ params,
                    float* __restrict__ out) {
    const int tid = blockIdx.x * blockDim.x + threadIdx.x;
    if (tid >= C2 * NBLK) return;
    const int c2 = tid % C2;
    const int b  = tid / C2;
    const float fb   = params[1];
    const float gain = params[4];

    const float2* f2p = reinterpret_cast<const float2*>(filt);
    const float2* in2 = reinterpret_cast<const float2*>(input);
    float2*       o2  = reinterpret_cast<float2*>(out);

    float2 z = reinterpret_cast<const float2*>(Z)[b * C2 + c2];  // z at frame 16b
    int idx = (b * CKPT) * C2 + c2;
    #pragma unroll
    for (int t = 0; t < CKPT; t += 4) {
        const float2 fa = f2p[idx];
        const float2 fbv = f2p[idx + C2];
        const float2 fc = f2p[idx + 2 * C2];
        const float2 fd = f2p[idx + 3 * C2];
        const float2 i0 = in2[idx];
        const float2 i1 = in2[idx + C2];
        const float2 i2v = in2[idx + 2 * C2];
        const float2 i3 = in2[idx + 3 * C2];
        float2 o;
        o.x = (i0.x + z.x) * gain;  o.y = (i0.y + z.y) * gain;  o2[idx] = o;
        z.x = fb * (z.x + fa.x);    z.y = fb * (z.y + fa.y);
        o.x = (i1.x + z.x) * gain;  o.y = (i1.y + z.y) * gain;  o2[idx + C2] = o;
        z.x = fb * (z.x + fbv.x);   z.y = fb * (z.y + fbv.y);
        o.x = (i2v.x + z.x) * gain; o.y = (i2v.y + z.y) * gain; o2[idx + 2 * C2] = o;
        z.x = fb * (z.x + fc.x);    z.y = fb * (z.y + fc.y);
        o.x = (i3.x + z.x) * gain;  o.y = (i3.y + z.y) * gain;  o2[idx + 3 * C2] = o;
        z.x = fb * (z.x + fd.x);    z.y = fb * (z.y + fd.y);
        idx += 4 * C2;
    }
}

extern "C" void kernel_launch(void* const* d_in, const int* in_sizes, int n_in,
                              void* d_out, int out_size, void* d_ws, size_t ws_size,
                              hipStream_t stream) {
    const float* input  = (const float*)d_in[0];
    const float* buf    = (const float*)d_in[1];
    const float* params = (const float*)d_in[2];
    float* out  = (float*)d_out;
    float* filt = (float*)d_ws;                          // 31.5 MB
    float* S    = filt + N_SAMPLES;                      // 1.97 MB
    float* Z    = S + C2 * 2 * NBLK;                     // 1.97 MB

    filter_kernel<<<N_SAMPLES / TILE1, BLK1, 0, stream>>>(buf, params, filt);

    const int tK = C2 * NBLK;                            // 245760
    sums_kernel<<<(tK + 255) / 256, 256, 0, stream>>>(filt, params, S);
    scan_kernel<<<(C2 + 255) / 256, 256, 0, stream>>>(S, params, Z);
    produce_kernel<<<(tK + 255) / 256, 256, 0, stream>>>(filt, input, Z, params, out);
}

// Round 13
// 132.923 us; speedup vs baseline: 1.2550x; 1.2550x over previous
//
#include <hip/hip_runtime.h>
#include <math.h>

// Resonator: out = (input + comb(bandpass(delay_buffer))) * gain
//
// bandpass: y1[n]=a1*y1[n-1]+(1-a1)*x[n]; y2[n]=a2*y2[n-1]+(1-a2)*a1*(x[n]-y1[n-1])
// comb over frames j (L=960): z[j] = fb*(filt[j-1]+z[j-1]), z[0]=0
//
// Pipeline (exact except filter's 256-sample zero-state halo, a1^256~1.2e-3):
//   K1 filter:  buf -> filt                         (LDS-staged, skew-36, b128)
//   K2 sums:    S[b][c] = sum_t fb^(16-t) filt[16b+t][c]    (reads filt once)
//   K3 scan:    Kogge-Stone in LDS per column: Z[b] = sum_{i<b} fb16^(b-1-i) S_i
//   K4 produce: from Z checkpoint, 16 frames/thread, each element touched once
//
// R11 lesson: serial K3 with sv[32] batching spilled to scratch (VGPR=36 < 64
// needed) and ran 42.9 us at 0.075% occupancy. Kogge-Stone removes both the
// serial chain and the register array.

constexpr int N_SAMPLES = 7864320;
constexpr int L_FRAME   = 960;
constexpr int K_FRAMES  = 8192;
constexpr int CKPT      = 16;
constexpr int NBLK      = K_FRAMES / CKPT;   // 512
constexpr int C2        = L_FRAME / 2;       // 480 float2 columns

// ---- K1: filter ----
constexpr int T1    = 32;
constexpr int BLK1  = 256;
constexpr int TILE1 = BLK1 * T1;             // 8192
constexpr int HALO1 = 256;
constexpr int STAGE_F4 = (TILE1 + HALO1) / 4;          // 2112
__device__ __forceinline__ int skew(int b) { return b + 4 * (b >> 5); }
constexpr int XS_FLOATS = (TILE1 + HALO1) + 4 * ((TILE1 + HALO1) / 32) + 4;

__global__ __launch_bounds__(256)
void filter_kernel(const float* __restrict__ buf,
                   const float* __restrict__ params,
                   float* __restrict__ filt) {
    __shared__ __align__(16) float xs[XS_FLOATS];   // ~38 KB -> 4 blocks/CU
    const int t     = threadIdx.x;
    const int tile0 = blockIdx.x * TILE1;

    const float4* b4 = reinterpret_cast<const float4*>(buf);
    const int g0 = tile0 / 4 - HALO1 / 4;
    for (int i = t; i < STAGE_F4; i += BLK1) {
        const int gi = g0 + i;
        const float4 v = (gi >= 0) ? b4[gi] : make_float4(0.f, 0.f, 0.f, 0.f);
        *reinterpret_cast<float4*>(&xs[skew(4 * i)]) = v;
    }
    __syncthreads();

    const float TPS = 6.28318530717958647692f / 48000.0f;
    const float a1 = expf(-TPS * params[2]);
    const float a2 = expf(-TPS * params[3]);
    const float k1 = 1.0f - a1;
    const float k2 = (1.0f - a2) * a1;

    float y1 = 0.f, y2 = 0.f;
    float o[T1];

#define FSTEP(v) do { float xv = (v); y2 = a2*y2 + k2*(xv - y1); y1 = a1*y1 + k1*xv; } while (0)
    for (int s = 0; s < 8; ++s) {           // warm-up [t*32, t*32+256)
        const int base = 36 * (t + s);
        #pragma unroll
        for (int r4 = 0; r4 < 8; ++r4) {
            const float4 x = *reinterpret_cast<const float4*>(&xs[base + 4 * r4]);
            FSTEP(x.x); FSTEP(x.y); FSTEP(x.z); FSTEP(x.w);
        }
    }
    {   // produce [t*32+256, t*32+288)
        const int base = 36 * (t + 8);
        #pragma unroll
        for (int r4 = 0; r4 < 8; ++r4) {
            const float4 x = *reinterpret_cast<const float4*>(&xs[base + 4 * r4]);
            FSTEP(x.x); o[4*r4]   = y2;
            FSTEP(x.y); o[4*r4+1] = y2;
            FSTEP(x.z); o[4*r4+2] = y2;
            FSTEP(x.w); o[4*r4+3] = y2;
        }
    }
#undef FSTEP
    __syncthreads();
    {
        const int base = 36 * t;
        #pragma unroll
        for (int r4 = 0; r4 < 8; ++r4)
            *reinterpret_cast<float4*>(&xs[base + 4 * r4]) =
                make_float4(o[4*r4], o[4*r4+1], o[4*r4+2], o[4*r4+3]);
    }
    __syncthreads();
    float4* f4 = reinterpret_cast<float4*>(filt);
    for (int i = t; i < TILE1 / 4; i += BLK1)
        f4[tile0 / 4 + i] = *reinterpret_cast<const float4*>(&xs[skew(4 * i)]);
}

// ---- K2: S[b][c2] = sum_t fb^(CKPT-t) filt[CKPT*b+t][c2] ----
__global__ __launch_bounds__(256)
void sums_kernel(const float* __restrict__ filt,
                 const float* __restrict__ params,
                 float* __restrict__ S) {
    const int tid = blockIdx.x * blockDim.x + threadIdx.x;
    if (tid >= C2 * NBLK) return;
    const int c2 = tid % C2;
    const int b  = tid / C2;
    const float fb = params[1];

    const float2* f2p = reinterpret_cast<const float2*>(filt);
    float2 s = make_float2(0.f, 0.f);
    int idx = (b * CKPT) * C2 + c2;
    #pragma unroll
    for (int t = 0; t < CKPT; t += 4) {
        const float2 f0 = f2p[idx];
        const float2 f1 = f2p[idx + C2];
        const float2 f2v = f2p[idx + 2 * C2];
        const float2 f3 = f2p[idx + 3 * C2];
        s.x = fb * (s.x + f0.x);  s.y = fb * (s.y + f0.y);
        s.x = fb * (s.x + f1.x);  s.y = fb * (s.y + f1.y);
        s.x = fb * (s.x + f2v.x); s.y = fb * (s.y + f2v.y);
        s.x = fb * (s.x + f3.x);  s.y = fb * (s.y + f3.y);
        idx += 4 * C2;
    }
    reinterpret_cast<float2*>(S)[b * C2 + c2] = s;   // z[16(b+1)] = fb^16 z[16b] + S_b
}

// ---- K3: Kogge-Stone scan in LDS; one 512-thread block per float2 column ----
// Inclusive scan y[b] = sum_{i<=b} fb16^(b-i) S_i; Z[b] = y[b-1] (Z[0]=0).
__global__ __launch_bounds__(512)
void scan_kernel(const float* __restrict__ S,
                 const float* __restrict__ params,
                 float* __restrict__ Z) {
    __shared__ float2 ls[NBLK];             // 4 KB
    const int b  = threadIdx.x;             // 0..511
    const int c2 = blockIdx.x;              // 0..479
    const float fb = params[1];
    float w = fb;                           // fb^16 by repeated squaring
    for (int i = 0; i < 4; ++i) w *= w;

    const float2* S2 = reinterpret_cast<const float2*>(S);
    float2*       Z2 = reinterpret_cast<float2*>(Z);

    ls[b] = S2[b * C2 + c2];
    __syncthreads();

    #pragma unroll
    for (int d = 1; d < NBLK; d <<= 1) {    // 9 steps
        float2 v = ls[b];
        const float2 p = (b >= d) ? ls[b - d] : make_float2(0.f, 0.f);
        __syncthreads();
        v.x += w * p.x;
        v.y += w * p.y;
        ls[b] = v;
        __syncthreads();
        w *= w;
    }
    const float2 zv = (b == 0) ? make_float2(0.f, 0.f) : ls[b - 1];
    Z2[b * C2 + c2] = zv;
}

// ---- K4: produce output; each element touched exactly once ----
__global__ __launch_bounds__(256)
void produce_kernel(const float* __restrict__ filt,
                    const float* __restrict__ input,
                    const float* __restrict__ Z,
                    const float* __restrict__ params,
                    float* __restrict__ out) {
    const int tid = blockIdx.x * blockDim.x + threadIdx.x;
    if (tid >= C2 * NBLK) return;
    const int c2 = tid % C2;
    const int b  = tid / C2;
    const float fb   = params[1];
    const float gain = params[4];

    const float2* f2p = reinterpret_cast<const float2*>(filt);
    const float2* in2 = reinterpret_cast<const float2*>(input);
    float2*       o2  = reinterpret_cast<float2*>(out);

    float2 z = reinterpret_cast<const float2*>(Z)[b * C2 + c2];  // z at frame 16b
    int idx = (b * CKPT) * C2 + c2;
    #pragma unroll
    for (int t = 0; t < CKPT; t += 4) {
        const float2 fa = f2p[idx];
        const float2 fbv = f2p[idx + C2];
        const float2 fc = f2p[idx + 2 * C2];
        const float2 fd = f2p[idx + 3 * C2];
        const float2 i0 = in2[idx];
        const float2 i1 = in2[idx + C2];
        const float2 i2v = in2[idx + 2 * C2];
        const float2 i3 = in2[idx + 3 * C2];
        float2 o;
        o.x = (i0.x + z.x) * gain;  o.y = (i0.y + z.y) * gain;  o2[idx] = o;
        z.x = fb * (z.x + fa.x);    z.y = fb * (z.y + fa.y);
        o.x = (i1.x + z.x) * gain;  o.y = (i1.y + z.y) * gain;  o2[idx + C2] = o;
        z.x = fb * (z.x + fbv.x);   z.y = fb * (z.y + fbv.y);
        o.x = (i2v.x + z.x) * gain; o.y = (i2v.y + z.y) * gain; o2[idx + 2 * C2] = o;
        z.x = fb * (z.x + fc.x);    z.y = fb * (z.y + fc.y);
        o.x = (i3.x + z.x) * gain;  o.y = (i3.y + z.y) * gain;  o2[idx + 3 * C2] = o;
        z.x = fb * (z.x + fd.x);    z.y = fb * (z.y + fd.y);
        idx += 4 * C2;
    }
}

extern "C" void kernel_launch(void* const* d_in, const int* in_sizes, int n_in,
                              void* d_out, int out_size, void* d_ws, size_t ws_size,
                              hipStream_t stream) {
    const float* input  = (const float*)d_in[0];
    const float* buf    = (const float*)d_in[1];
    const float* params = (const float*)d_in[2];
    float* out  = (float*)d_out;
    float* filt = (float*)d_ws;                          // 31.5 MB
    float* S    = filt + N_SAMPLES;                      // 1.97 MB
    float* Z    = S + C2 * 2 * NBLK;                     // 1.97 MB

    filter_kernel<<<N_SAMPLES / TILE1, BLK1, 0, stream>>>(buf, params, filt);

    const int tK = C2 * NBLK;                            // 245760
    sums_kernel<<<(tK + 255) / 256, 256, 0, stream>>>(filt, params, S);
    scan_kernel<<<C2, NBLK, 0, stream>>>(S, params, Z);
    produce_kernel<<<(tK + 255) / 256, 256, 0, stream>>>(filt, input, Z, params, out);
}